// Round 5
// baseline (6726.954 us; speedup 1.0000x reference)
//
#include <hip/hip_runtime.h>
#include <hip/hip_bf16.h>
#include <stdint.h>

#define TT 512
#define BB 256
#define DD 512
#define HH 256
#define AA 32
#define NG 1024  // 4*H

#define NPROD 128   // persistent producer blocks: 32+128=160 <= 256 CUs, and
                    // 128 CUs * (1 tile / ~20us) = 6.4 tiles/us > scan's ~5.5
                    // consumption -> natural pacing, no throttle state at all

using f32x4 = __attribute__((ext_vector_type(4))) float;
using bf8   = __attribute__((ext_vector_type(8))) short;

static __device__ __forceinline__ short f2bf(float f) {
  union { float f; uint32_t u; } v; v.f = f;
  uint32_t u = v.u;
  u = u + 0x7fffu + ((u >> 16) & 1u);   // round-to-nearest-even
  return (short)(u >> 16);
}
static __device__ __forceinline__ float bf2f(unsigned short s) {
  union { uint32_t u; float f; } v; v.u = ((uint32_t)s) << 16;
  return v.f;
}
static __device__ __forceinline__ float sigf(float x) {
  return 1.0f / (1.0f + __expf(-x));
}
static __device__ __forceinline__ float tanh_(float x) {
  float e = __expf(2.0f * x);
  return 1.0f - 2.0f / (e + 1.0f);   // safe at +/-inf
}

// ---- workspace layout ----
static constexpr size_t XP_OFF    = 0;                              // bf16 [T*B][1024]
static constexpr size_t XP_BYTES  = (size_t)TT * BB * NG * 2;       // 268435456
static constexpr size_t WXT_OFF   = XP_OFF + XP_BYTES;              // bf16 [1024][512]
static constexpr size_t WXT_BYTES = (size_t)NG * DD * 2;            // 1048576
// tagged mail: u32 {low16 = bf16 h, high16 = tag = t+1}
// [parity 2][grp 16][half 2][row 16][hcol 128]
static constexpr size_t MAIL_OFF  = WXT_OFF + WXT_BYTES;
static constexpr size_t MAIL_BYTES= (size_t)2 * 16 * 2 * 16 * 128 * 4;  // 524288
// per-timestep xp readiness tags: u32 done[T][16], value 0x5EED0000|t.
// Poison 0xAAAAAAAA never matches; no init needed (harness poisons ws).
static constexpr size_t DONE_OFF   = MAIL_OFF + MAIL_BYTES;
static constexpr size_t DONE_BYTES = (size_t)TT * 16 * 4;           // 32768
static constexpr size_t WS_NEEDED      = MAIL_OFF + MAIL_BYTES;     // legacy path
static constexpr size_t WS_NEEDED_FUSE = DONE_OFF + DONE_BYTES;     // fused path

// Wx [512][1024] fp32 -> WxT [1024][512] bf16
__global__ __launch_bounds__(256) void transpose_wx_kernel(
    const float* __restrict__ Wx, unsigned short* __restrict__ WxT) {
  __shared__ float tile[32][33];
  int bx = blockIdx.x;
  int k0 = (bx & 15) * 32;
  int n0 = (bx >> 4) * 32;
  int r = threadIdx.x >> 5;
  int c = threadIdx.x & 31;
  #pragma unroll
  for (int i = 0; i < 4; ++i) {
    int rr = r + i * 8;
    tile[rr][c] = Wx[(size_t)(k0 + rr) * NG + n0 + c];
  }
  __syncthreads();
  #pragma unroll
  for (int i = 0; i < 4; ++i) {
    int rr = r + i * 8;
    WxT[(size_t)(n0 + rr) * DD + k0 + c] = (unsigned short)f2bf(tile[c][rr]);
  }
}

// ---- legacy standalone xproj GEMM (fallback when ws lacks done[] space) ----
__global__ __launch_bounds__(256) void gemm_xproj(
    const float* __restrict__ X,
    const unsigned short* __restrict__ WxT,  // [n][k] bf16
    const float* __restrict__ bias,
    unsigned short* __restrict__ xp) {
  __shared__ short As[128][72];
  __shared__ short Bs[128][72];
  const int tid  = threadIdx.x;
  const int lane = tid & 63;
  const int wave = tid >> 6;
  const int quad = lane >> 4;
  const int l15  = lane & 15;
  const int wm = wave >> 1, wn = wave & 1;
  const int bid = blockIdx.x;
  const int m0 = (bid >> 3) * 128;
  const int n0 = (bid & 7) * 128;

  f32x4 acc[4][4];
  #pragma unroll
  for (int i = 0; i < 4; ++i)
    #pragma unroll
    for (int j = 0; j < 4; ++j) acc[i][j] = (f32x4){0.f, 0.f, 0.f, 0.f};

  for (int kt = 0; kt < 8; ++kt) {
    const int k0 = kt * 64;
    #pragma unroll
    for (int jj = 0; jj < 4; ++jj) {
      int c = tid + jj * 256;
      int row = c >> 3;
      int kc = (c & 7) * 8;
      const float4* src = (const float4*)(X + (size_t)(m0 + row) * DD + k0 + kc);
      float4 v0 = src[0];
      float4 v1 = src[1];
      bf8 tv;
      tv[0] = f2bf(v0.x); tv[1] = f2bf(v0.y); tv[2] = f2bf(v0.z); tv[3] = f2bf(v0.w);
      tv[4] = f2bf(v1.x); tv[5] = f2bf(v1.y); tv[6] = f2bf(v1.z); tv[7] = f2bf(v1.w);
      *(bf8*)&As[row][kc] = tv;
      const uint4* bsrc = (const uint4*)(WxT + (size_t)(n0 + row) * DD + k0 + kc);
      *(uint4*)&Bs[row][kc] = *bsrc;
    }
    __syncthreads();
    #pragma unroll
    for (int ks = 0; ks < 2; ++ks) {
      bf8 a[4], b[4];
      #pragma unroll
      for (int mt = 0; mt < 4; ++mt)
        a[mt] = *(const bf8*)&As[wm * 64 + mt * 16 + l15][ks * 32 + quad * 8];
      #pragma unroll
      for (int nt = 0; nt < 4; ++nt)
        b[nt] = *(const bf8*)&Bs[wn * 64 + nt * 16 + l15][ks * 32 + quad * 8];
      #pragma unroll
      for (int mt = 0; mt < 4; ++mt)
        #pragma unroll
        for (int nt = 0; nt < 4; ++nt)
          acc[mt][nt] = __builtin_amdgcn_mfma_f32_16x16x32_bf16(a[mt], b[nt], acc[mt][nt], 0, 0, 0);
    }
    __syncthreads();
  }
  #pragma unroll
  for (int mt = 0; mt < 4; ++mt)
    #pragma unroll
    for (int nt = 0; nt < 4; ++nt) {
      int col = n0 + wn * 64 + nt * 16 + l15;
      float bv = bias[col];
      #pragma unroll
      for (int r = 0; r < 4; ++r) {
        int row = m0 + wm * 64 + mt * 16 + quad * 4 + r;
        xp[(size_t)row * NG + col] = (unsigned short)f2bf(acc[mt][nt][r] + bv);
      }
    }
}

// ---- shared scan body: own-half-early schedule ----
// Block p owns h-cols [128p, 128p+128) = MFMA k-slices {4p..4p+3}; those
// A-fragments come from the block's OWN gate outputs. Per step:
//   F: gates -> own h_lds write + mail store (tag t+1)
//   G: finish heads (partner ks) -> out[t-1]
//   H: barrier; I: read own af, issue own-half z-MFMAs + own-half heads
//      (this work rides INSIDE the mail flight window)
//   next iter: A prefetch; B spin partner mail; C barrier;
//   D/E: partner af + remaining 4 ks -> z complete -> F gates.
// Critical store-to-store path: observe + 4-ks MFMA + gates (was 8-ks).
// Protocol identical to the round-4 passing config: tagged mail, RELEASE
// done tag, agent-scope xp atomic loads (stale-L2-proof).
template <bool FUSED>
static __device__ __forceinline__ void scan_body(
    char* smem,
    const unsigned short* __restrict__ xp,
    const int* __restrict__ is_new,
    const float* __restrict__ carry_c,
    const float* __restrict__ carry_h,
    const float* __restrict__ Wh,
    const float* __restrict__ Wa,
    const float* __restrict__ ba,
    const float* __restrict__ Wv,
    const float* __restrict__ bv,
    float* __restrict__ out,
    unsigned int* __restrict__ mail,
    unsigned int* __restrict__ done) {
  const int tid  = threadIdx.x;
  const int lane = tid & 63;
  const int w    = tid >> 6;          // wave 0..7
  const int quad = (lane >> 4);
  const int l15  = lane & 15;
  const int bid  = blockIdx.x;        // 0..31
  const int grp  = bid >> 1;
  const int p    = bid & 1;           // half
  const int s    = p * 8 + w;         // j-slice 0..15
  const int b0   = grp * 16;
  const int j0   = s * 16;
  const int ko   = 4 * p;             // own k-slices {ko..ko+3}
  const int kq   = 4 * (1 - p);       // partner k-slices

  short (*h_lds)[264]  = (short (*)[264])smem;           // bf16 full rows, +8 pad
  int   (*flag_lds)[16] = (int (*)[16])(smem + 8448);    // dbuf by t&1

  // ---- loop-invariant Wh B-fragments -> 128 VGPRs ----
  bf8 whb[4][8];
  #pragma unroll
  for (int nt = 0; nt < 4; ++nt)
    #pragma unroll
    for (int ks = 0; ks < 8; ++ks)
      #pragma unroll
      for (int j = 0; j < 8; ++j) {
        int k = ks * 32 + quad * 8 + j;            // B-frag: k = quad*8+j, n = lane&15
        int col = nt * 256 + j0 + l15;
        whb[nt][ks][j] = f2bf(Wh[(size_t)k * NG + col]);
      }
  // ---- Wa/Wv B-fragments (head GEMM) ----
  const int astart = (s < 15) ? (2 * s) : 30;
  const int ncols  = (s < 15) ? 2 : 3;
  bf8 wab[8];
  #pragma unroll
  for (int ks = 0; ks < 8; ++ks)
    #pragma unroll
    for (int j = 0; j < 8; ++j) {
      int k = ks * 32 + quad * 8 + j;
      float v = 0.0f;
      if (l15 < ncols) {
        int a = astart + l15;
        v = (a < 32) ? Wa[(size_t)k * 32 + a] : Wv[k];
      }
      wab[ks][j] = f2bf(v);
    }
  float obias = 0.0f;
  if (l15 < ncols) {
    int a = astart + l15;
    obias = (a < 32) ? ba[a] : bv[0];
  }
  // ---- carry c in registers ----
  float c4[4];
  #pragma unroll
  for (int r = 0; r < 4; ++r)
    c4[r] = carry_c[(size_t)(b0 + quad * 4 + r) * HH + j0 + l15];

  const int crow = tid >> 5;          // 0..15
  const int cc0  = (tid & 31) * 4;    // 0..124

  bool rdy = false;                   // done[t] already confirmed (lookahead)
  f32x4 zacc[4];                      // carried: own-half started at I
  f32x4 oacc = (f32x4){0.f, 0.f, 0.f, 0.f};  // carried: heads own-half at I
  #pragma unroll
  for (int nt = 0; nt < 4; ++nt) zacc[nt] = (f32x4){0.f, 0.f, 0.f, 0.f};

  #pragma unroll 1
  for (int t = 0; t <= TT; ++t) {
    const bool last = (t == TT);
    unsigned short xpraw[16];
    unsigned int dv = 0u;             // lookahead sample of done[t+1]
    // ---- A: prefetch xp + flags (+ done gate) ----
    if (!last) {
      if constexpr (FUSED) {
        if (!rdy) {
          const unsigned int want = 0x5EED0000u | (unsigned)t;
          unsigned int* dp = done + (size_t)t * 16 + l15;
          int g2 = 0;
          for (;;) {
            unsigned int v = __hip_atomic_load(dp, __ATOMIC_RELAXED, __HIP_MEMORY_SCOPE_AGENT);
            if (__all((int)(v == want))) break;
            __builtin_amdgcn_s_sleep(8);
            if (++g2 > (1 << 20)) break;   // anti-hang bailout
          }
        }
        __atomic_signal_fence(__ATOMIC_ACQUIRE);
      }
      #pragma unroll
      for (int nt = 0; nt < 4; ++nt)
        #pragma unroll
        for (int r = 0; r < 4; ++r) {
          size_t row = (size_t)t * BB + b0 + quad * 4 + r;
          if constexpr (FUSED) {
            size_t col = (size_t)nt * 256 + j0 + (l15 & ~1);
            unsigned int v = __hip_atomic_load(
                (unsigned int*)(xp + row * NG + col),
                __ATOMIC_RELAXED, __HIP_MEMORY_SCOPE_AGENT);
            xpraw[nt * 4 + r] =
                (unsigned short)((l15 & 1) ? (v >> 16) : (v & 0xFFFFu));
          } else {
            xpraw[nt * 4 + r] = xp[row * NG + nt * 256 + j0 + l15];
          }
        }
      if (tid < 16) flag_lds[t & 1][tid] = is_new[t * BB + b0 + tid];
      if constexpr (FUSED) {
        if (t + 1 < TT)
          dv = __hip_atomic_load(done + (size_t)(t + 1) * 16 + l15,
                                 __ATOMIC_RELAXED, __HIP_MEMORY_SCOPE_AGENT);
      }
    }
    // ---- B: partner-half staging ----
    if (t > 0) {
      unsigned long long* mp = (unsigned long long*)
          (mail + ((((size_t)(t & 1) * 16 + grp) * 2 + (1 - p)) * 2048)
                + (size_t)crow * 128 + cc0);
      const unsigned long long M = 0xFFFF0000FFFF0000ull;
      const unsigned long long Wt = ((unsigned long long)(unsigned)t << 16)
                                  | ((unsigned long long)(unsigned)t << 48);
      unsigned long long pv0, pv1;
      int guard = 0;
      for (;;) {
        pv0 = __hip_atomic_load(&mp[0], __ATOMIC_RELAXED, __HIP_MEMORY_SCOPE_AGENT);
        pv1 = __hip_atomic_load(&mp[1], __ATOMIC_RELAXED, __HIP_MEMORY_SCOPE_AGENT);
        bool ok = ((pv0 & M) == Wt) && ((pv1 & M) == Wt);
        if (__all((int)ok)) break;
        __builtin_amdgcn_s_sleep(1);
        if (++guard > (1 << 24)) break;   // anti-hang bailout
      }
      __atomic_signal_fence(__ATOMIC_ACQUIRE);
      unsigned long long packed =
            (pv0 & 0xFFFFull)
          | (((pv0 >> 32) & 0xFFFFull) << 16)
          | ((pv1 & 0xFFFFull) << 32)
          | (((pv1 >> 32) & 0xFFFFull) << 48);
      *(unsigned long long*)&h_lds[crow][(1 - p) * 128 + cc0] = packed;
    } else {
      // t==0: stage full rows from carry_h (fp32 -> bf16)
      int row  = tid >> 5;
      int col0 = (tid & 31) * 8;
      const float4* src = (const float4*)(carry_h + (size_t)(b0 + row) * HH + col0);
      float4 a = src[0], b4 = src[1];
      bf8 tv;
      tv[0] = f2bf(a.x);  tv[1] = f2bf(a.y);  tv[2] = f2bf(a.z);  tv[3] = f2bf(a.w);
      tv[4] = f2bf(b4.x); tv[5] = f2bf(b4.y); tv[6] = f2bf(b4.z); tv[7] = f2bf(b4.w);
      *(bf8*)&h_lds[row][col0] = tv;
    }
    __syncthreads();   // C: staging complete
    // ---- D/E: finish z (partner ks); afp kept for heads at G ----
    bf8 afp[4];
    if (t == 0) {
      // boot: full h staged -> full 8-ks z for step 0
      bf8 af0[8];
      #pragma unroll
      for (int ks = 0; ks < 8; ++ks)
        af0[ks] = *(const bf8*)&h_lds[l15][ks * 32 + quad * 8];
      __syncthreads();   // reads done before own-col overwrite at F
      #pragma unroll
      for (int nt = 0; nt < 4; ++nt) zacc[nt] = (f32x4){0.f, 0.f, 0.f, 0.f};
      #pragma unroll
      for (int ks = 0; ks < 8; ++ks)
        #pragma unroll
        for (int nt = 0; nt < 4; ++nt)
          zacc[nt] = __builtin_amdgcn_mfma_f32_16x16x32_bf16(af0[ks], whb[nt][ks], zacc[nt], 0, 0, 0);
    } else {
      #pragma unroll
      for (int i = 0; i < 4; ++i)
        afp[i] = *(const bf8*)&h_lds[l15][(kq + i) * 32 + quad * 8];
      if (!last) {
        #pragma unroll
        for (int i = 0; i < 4; ++i)
          #pragma unroll
          for (int nt = 0; nt < 4; ++nt)
            zacc[nt] = __builtin_amdgcn_mfma_f32_16x16x32_bf16(afp[i], whb[nt][kq + i], zacc[nt], 0, 0, 0);
      }
    }
    // ---- F: gates; episode reset folded in at the gate level ----
    if (!last) {
      unsigned int* mout = mail + ((((size_t)((t + 1) & 1) * 16 + grp) * 2 + p) * 2048);
      const unsigned int tag = (unsigned int)(t + 1) << 16;
      #pragma unroll
      for (int r = 0; r < 4; ++r) {
        int fr = flag_lds[t & 1][quad * 4 + r];
        float zi = (fr ? 0.0f : zacc[0][r]) + bf2f(xpraw[0 * 4 + r]);
        float zf = (fr ? 0.0f : zacc[1][r]) + bf2f(xpraw[1 * 4 + r]);
        float zg = (fr ? 0.0f : zacc[2][r]) + bf2f(xpraw[2 * 4 + r]);
        float zo = (fr ? 0.0f : zacc[3][r]) + bf2f(xpraw[3 * 4 + r]);
        float ce = fr ? 0.0f : c4[r];
        float ncv = sigf(zf) * ce + sigf(zi) * tanh_(zg);
        c4[r] = ncv;
        float nh = sigf(zo) * tanh_(ncv);
        unsigned short hv = (unsigned short)f2bf(nh);
        int row = quad * 4 + r;
        h_lds[row][j0 + l15] = (short)hv;                 // own half, block-local
        __hip_atomic_store(&mout[(size_t)row * 128 + w * 16 + l15],
                           (unsigned int)hv | tag,
                           __ATOMIC_RELAXED, __HIP_MEMORY_SCOPE_AGENT);
      }
    }
    if constexpr (FUSED) {
      rdy = (!last && (t + 1 < TT))
          ? (bool)__all((int)(dv == (0x5EED0000u | (unsigned)(t + 1))))
          : false;
    }
    // ---- G: finish heads (partner ks) -> out[t-1] ----
    if (t > 0) {
      #pragma unroll
      for (int i = 0; i < 4; ++i)
        oacc = __builtin_amdgcn_mfma_f32_16x16x32_bf16(afp[i], wab[kq + i], oacc, 0, 0, 0);
      if (l15 < ncols) {
        #pragma unroll
        for (int r = 0; r < 4; ++r) {
          size_t orow = (size_t)(t - 1) * BB + b0 + quad * 4 + r;
          out[orow * 33 + astart + l15] = oacc[r] + obias;
        }
      }
    }
    // ---- H+I: own-half start for step t+1 (rides the mail flight) ----
    if (!last) {
      __syncthreads();   // H: own h(t+1) writes visible
      bf8 afo[4];
      #pragma unroll
      for (int i = 0; i < 4; ++i)
        afo[i] = *(const bf8*)&h_lds[l15][(ko + i) * 32 + quad * 8];
      #pragma unroll
      for (int nt = 0; nt < 4; ++nt) zacc[nt] = (f32x4){0.f, 0.f, 0.f, 0.f};
      #pragma unroll
      for (int i = 0; i < 4; ++i)
        #pragma unroll
        for (int nt = 0; nt < 4; ++nt)
          zacc[nt] = __builtin_amdgcn_mfma_f32_16x16x32_bf16(afo[i], whb[nt][ko + i], zacc[nt], 0, 0, 0);
      oacc = (f32x4){0.f, 0.f, 0.f, 0.f};
      #pragma unroll
      for (int i = 0; i < 4; ++i)
        oacc = __builtin_amdgcn_mfma_f32_16x16x32_bf16(afo[i], wab[ko + i], oacc, 0, 0, 0);
    }
  }
}

// legacy standalone scan (fallback)
__global__ __launch_bounds__(512, 1) void scan_kernel(
    const unsigned short* __restrict__ xp,
    const int* __restrict__ is_new,
    const float* __restrict__ carry_c,
    const float* __restrict__ carry_h,
    const float* __restrict__ Wh,
    const float* __restrict__ Wa,
    const float* __restrict__ ba,
    const float* __restrict__ Wv,
    const float* __restrict__ bv,
    float* __restrict__ out,
    unsigned int* __restrict__ mail) {
  __shared__ __align__(16) char smem[8576];
  scan_body<false>(smem, xp, is_new, carry_c, carry_h, Wh, Wa, ba, Wv, bv,
                   out, mail, nullptr);
}

// ---- fused producer-consumer kernel ----
// blocks 0..31: persistent scan. blocks 32..159: persistent GEMM producers
// (tile stride NPROD, naturally paced by count -- round-4 lesson: NO shared
// throttle state; 192 spinners on one prog line cost +786us). LDS 84KB
// forces 1 block/CU (round-1 lesson); 160 blocks <= 256 CUs => all resident.
__global__ __launch_bounds__(512, 1) void fused_kernel(
    const float* __restrict__ X,
    const unsigned short* __restrict__ WxT,
    const float* __restrict__ bias,
    unsigned short* __restrict__ xp,
    const int* __restrict__ is_new,
    const float* __restrict__ carry_c,
    const float* __restrict__ carry_h,
    const float* __restrict__ Wh,
    const float* __restrict__ Wa,
    const float* __restrict__ ba,
    const float* __restrict__ Wv,
    const float* __restrict__ bv,
    float* __restrict__ out,
    unsigned int* __restrict__ mail,
    unsigned int* __restrict__ done) {
  __shared__ __align__(16) char smem[86016];  // 84KB: forces 1 block/CU
  const int tid = threadIdx.x;
  if (blockIdx.x >= 32) {
    // ---------------- persistent GEMM producer ----------------
    short (*As)[72] = (short (*)[72])smem;
    short (*Bs)[72] = (short (*)[72])(smem + 18432);
    short* xps = (short*)smem;        // epilogue staging, overlays As/Bs
    const int lane = tid & 63;
    const int wave = tid >> 6;        // 0..7
    const int quad = lane >> 4;
    const int l15  = lane & 15;
    const int wm = wave >> 1;         // 0..3  (32 rows each)
    const int wn = wave & 1;          // 0..1  (64 cols each)
    const int pid = (int)blockIdx.x - 32;

    for (int tile = pid; tile < 8192; tile += NPROD) {
      const int mtile = tile >> 3;    // 0..1023, ascending per block
      const int nb    = tile & 7;
      const int t16   = mtile >> 1;   // timestep this tile belongs to
      const int m0 = mtile * 128;
      const int n0 = nb * 128;

      f32x4 acc[2][4];
      #pragma unroll
      for (int i = 0; i < 2; ++i)
        #pragma unroll
        for (int j = 0; j < 4; ++j) acc[i][j] = (f32x4){0.f, 0.f, 0.f, 0.f};

      for (int kt = 0; kt < 8; ++kt) {
        const int k0 = kt * 64;
        #pragma unroll
        for (int jj = 0; jj < 2; ++jj) {
          int c = tid + jj * 512;       // 1024 16B-chunks
          int row = c >> 3;
          int kc = (c & 7) * 8;
          const float4* src = (const float4*)(X + (size_t)(m0 + row) * DD + k0 + kc);
          float4 v0 = src[0];
          float4 v1 = src[1];
          bf8 tv;
          tv[0] = f2bf(v0.x); tv[1] = f2bf(v0.y); tv[2] = f2bf(v0.z); tv[3] = f2bf(v0.w);
          tv[4] = f2bf(v1.x); tv[5] = f2bf(v1.y); tv[6] = f2bf(v1.z); tv[7] = f2bf(v1.w);
          *(bf8*)&As[row][kc] = tv;
          const uint4* bsrc = (const uint4*)(WxT + (size_t)(n0 + row) * DD + k0 + kc);
          *(uint4*)&Bs[row][kc] = *bsrc;
        }
        __syncthreads();
        #pragma unroll
        for (int ks = 0; ks < 2; ++ks) {
          bf8 a[2], b[4];
          #pragma unroll
          for (int mt = 0; mt < 2; ++mt)
            a[mt] = *(const bf8*)&As[wm * 32 + mt * 16 + l15][ks * 32 + quad * 8];
          #pragma unroll
          for (int nt = 0; nt < 4; ++nt)
            b[nt] = *(const bf8*)&Bs[wn * 64 + nt * 16 + l15][ks * 32 + quad * 8];
          #pragma unroll
          for (int mt = 0; mt < 2; ++mt)
            #pragma unroll
            for (int nt = 0; nt < 4; ++nt)
              acc[mt][nt] = __builtin_amdgcn_mfma_f32_16x16x32_bf16(a[mt], b[nt], acc[mt][nt], 0, 0, 0);
        }
        __syncthreads();
      }
      // ---- epilogue: stage tile in LDS, then full-line coalesced stores ----
      #pragma unroll
      for (int mt = 0; mt < 2; ++mt)
        #pragma unroll
        for (int nt = 0; nt < 4; ++nt) {
          int lcol = wn * 64 + nt * 16 + l15;
          float bvv = bias[n0 + lcol];
          #pragma unroll
          for (int r = 0; r < 4; ++r) {
            int lrow = wm * 32 + mt * 16 + quad * 4 + r;
            xps[lrow * 136 + lcol] = f2bf(acc[mt][nt][r] + bvv);  // +8 pad rows
          }
        }
      __syncthreads();
      #pragma unroll
      for (int j = 0; j < 4; ++j) {
        int c = tid + j * 512;          // 2048 16B segments
        int row = c >> 4;
        int seg = c & 15;
        uint4 v = *(const uint4*)&xps[row * 136 + seg * 8];
        *(uint4*)(xp + (size_t)(m0 + row) * NG + n0 + seg * 8) = v;
      }
      __syncthreads();  // all waves: vmcnt drained (stores in L2), xps reads done
      if (tid == 0) {
        // RELEASE store: memory model guarantees all prior xp stores are
        // agent-visible before the tag lands.
        const int slot = (mtile & 1) * 8 + nb;
        __hip_atomic_store(&done[(size_t)t16 * 16 + slot],
                           0x5EED0000u | (unsigned)t16,
                           __ATOMIC_RELEASE, __HIP_MEMORY_SCOPE_AGENT);
      }
    }
    return;
  }
  // ---------------- scan consumer ----------------
  scan_body<true>(smem, xp, is_new, carry_c, carry_h, Wh, Wa, ba, Wv, bv,
                  out, mail, done);
}

extern "C" void kernel_launch(void* const* d_in, const int* in_sizes, int n_in,
                              void* d_out, int out_size, void* d_ws, size_t ws_size,
                              hipStream_t stream) {
  const float* X       = (const float*)d_in[0];
  const int* is_new    = (const int*)d_in[1];
  const float* carry_c = (const float*)d_in[2];
  const float* carry_h = (const float*)d_in[3];
  const float* Wx      = (const float*)d_in[4];
  const float* Wh      = (const float*)d_in[5];
  const float* b       = (const float*)d_in[6];
  const float* Wa      = (const float*)d_in[7];
  const float* ba      = (const float*)d_in[8];
  const float* Wv      = (const float*)d_in[9];
  const float* bv      = (const float*)d_in[10];
  float* out = (float*)d_out;
  char* ws = (char*)d_ws;
  if (ws_size < WS_NEEDED) return;  // diagnostic: out stays poisoned
  unsigned short* xp   = (unsigned short*)(ws + XP_OFF);
  unsigned short* WxT  = (unsigned short*)(ws + WXT_OFF);
  unsigned int* mail   = (unsigned int*)(ws + MAIL_OFF);

  hipLaunchKernelGGL(transpose_wx_kernel, dim3(512), dim3(256), 0, stream, Wx, WxT);
  if (ws_size >= WS_NEEDED_FUSE) {
    unsigned int* done = (unsigned int*)(ws + DONE_OFF);
    hipLaunchKernelGGL(fused_kernel, dim3(32 + NPROD), dim3(512), 0, stream,
                       X, WxT, b, xp, is_new, carry_c, carry_h, Wh, Wa, ba, Wv, bv,
                       out, mail, done);
  } else {
    hipLaunchKernelGGL(gemm_xproj, dim3(8192), dim3(256), 0, stream, X, WxT, b, xp);
    hipLaunchKernelGGL(scan_kernel, dim3(32), dim3(512), 0, stream,
                       xp, is_new, carry_c, carry_h, Wh, Wa, ba, Wv, bv, out, mail);
  }
}

// Round 6
// 3274.381 us; speedup vs baseline: 2.0544x; 2.0544x over previous
//
#include <hip/hip_runtime.h>
#include <hip/hip_bf16.h>
#include <stdint.h>

#define TT 512
#define BB 256
#define DD 512
#define HH 256
#define AA 32
#define NG 1024  // 4*H

#define NPROD 128   // persistent producer blocks: 32+128=160 <= 256 CUs.
                    // Pacing by COUNT (no shared throttle state -- round-4
                    // lesson). 128 producer CUs halve the instantaneous HBM
                    // pressure vs round-2's 224-CU burst.

using f32x4 = __attribute__((ext_vector_type(4))) float;
using bf8   = __attribute__((ext_vector_type(8))) short;

static __device__ __forceinline__ short f2bf(float f) {
  union { float f; uint32_t u; } v; v.f = f;
  uint32_t u = v.u;
  u = u + 0x7fffu + ((u >> 16) & 1u);   // round-to-nearest-even
  return (short)(u >> 16);
}
static __device__ __forceinline__ float bf2f(unsigned short s) {
  union { uint32_t u; float f; } v; v.u = ((uint32_t)s) << 16;
  return v.f;
}
static __device__ __forceinline__ float sigf(float x) {
  return 1.0f / (1.0f + __expf(-x));
}
static __device__ __forceinline__ float tanh_(float x) {
  float e = __expf(2.0f * x);
  return 1.0f - 2.0f / (e + 1.0f);   // safe at +/-inf
}

// ---- workspace layout ----
static constexpr size_t XP_OFF    = 0;                              // bf16 [T*B][1024]
static constexpr size_t XP_BYTES  = (size_t)TT * BB * NG * 2;       // 268435456
static constexpr size_t WXT_OFF   = XP_OFF + XP_BYTES;              // bf16 [1024][512]
static constexpr size_t WXT_BYTES = (size_t)NG * DD * 2;            // 1048576
// tagged mail: u32 {low16 = bf16 h, high16 = tag = t+1}
// [parity 2][grp 16][half 2][row 16][hcol 128]
static constexpr size_t MAIL_OFF  = WXT_OFF + WXT_BYTES;
static constexpr size_t MAIL_BYTES= (size_t)2 * 16 * 2 * 16 * 128 * 4;  // 524288
// per-timestep xp readiness tags: u32 done[T][16], value 0x5EED0000|t.
// Poison 0xAAAAAAAA never matches; no init needed (harness poisons ws).
static constexpr size_t DONE_OFF   = MAIL_OFF + MAIL_BYTES;
static constexpr size_t DONE_BYTES = (size_t)TT * 16 * 4;           // 32768
static constexpr size_t WS_NEEDED      = MAIL_OFF + MAIL_BYTES;     // legacy path
static constexpr size_t WS_NEEDED_FUSE = DONE_OFF + DONE_BYTES;     // fused path

// Wx [512][1024] fp32 -> WxT [1024][512] bf16
__global__ __launch_bounds__(256) void transpose_wx_kernel(
    const float* __restrict__ Wx, unsigned short* __restrict__ WxT) {
  __shared__ float tile[32][33];
  int bx = blockIdx.x;
  int k0 = (bx & 15) * 32;
  int n0 = (bx >> 4) * 32;
  int r = threadIdx.x >> 5;
  int c = threadIdx.x & 31;
  #pragma unroll
  for (int i = 0; i < 4; ++i) {
    int rr = r + i * 8;
    tile[rr][c] = Wx[(size_t)(k0 + rr) * NG + n0 + c];
  }
  __syncthreads();
  #pragma unroll
  for (int i = 0; i < 4; ++i) {
    int rr = r + i * 8;
    WxT[(size_t)(n0 + rr) * DD + k0 + c] = (unsigned short)f2bf(tile[c][rr]);
  }
}

// ---- legacy standalone xproj GEMM (fallback when ws lacks done[] space) ----
__global__ __launch_bounds__(256) void gemm_xproj(
    const float* __restrict__ X,
    const unsigned short* __restrict__ WxT,  // [n][k] bf16
    const float* __restrict__ bias,
    unsigned short* __restrict__ xp) {
  __shared__ short As[128][72];
  __shared__ short Bs[128][72];
  const int tid  = threadIdx.x;
  const int lane = tid & 63;
  const int wave = tid >> 6;
  const int quad = lane >> 4;
  const int l15  = lane & 15;
  const int wm = wave >> 1, wn = wave & 1;
  const int bid = blockIdx.x;
  const int m0 = (bid >> 3) * 128;
  const int n0 = (bid & 7) * 128;

  f32x4 acc[4][4];
  #pragma unroll
  for (int i = 0; i < 4; ++i)
    #pragma unroll
    for (int j = 0; j < 4; ++j) acc[i][j] = (f32x4){0.f, 0.f, 0.f, 0.f};

  for (int kt = 0; kt < 8; ++kt) {
    const int k0 = kt * 64;
    #pragma unroll
    for (int jj = 0; jj < 4; ++jj) {
      int c = tid + jj * 256;
      int row = c >> 3;
      int kc = (c & 7) * 8;
      const float4* src = (const float4*)(X + (size_t)(m0 + row) * DD + k0 + kc);
      float4 v0 = src[0];
      float4 v1 = src[1];
      bf8 tv;
      tv[0] = f2bf(v0.x); tv[1] = f2bf(v0.y); tv[2] = f2bf(v0.z); tv[3] = f2bf(v0.w);
      tv[4] = f2bf(v1.x); tv[5] = f2bf(v1.y); tv[6] = f2bf(v1.z); tv[7] = f2bf(v1.w);
      *(bf8*)&As[row][kc] = tv;
      const uint4* bsrc = (const uint4*)(WxT + (size_t)(n0 + row) * DD + k0 + kc);
      *(uint4*)&Bs[row][kc] = *bsrc;
    }
    __syncthreads();
    #pragma unroll
    for (int ks = 0; ks < 2; ++ks) {
      bf8 a[4], b[4];
      #pragma unroll
      for (int mt = 0; mt < 4; ++mt)
        a[mt] = *(const bf8*)&As[wm * 64 + mt * 16 + l15][ks * 32 + quad * 8];
      #pragma unroll
      for (int nt = 0; nt < 4; ++nt)
        b[nt] = *(const bf8*)&Bs[wn * 64 + nt * 16 + l15][ks * 32 + quad * 8];
      #pragma unroll
      for (int mt = 0; mt < 4; ++mt)
        #pragma unroll
        for (int nt = 0; nt < 4; ++nt)
          acc[mt][nt] = __builtin_amdgcn_mfma_f32_16x16x32_bf16(a[mt], b[nt], acc[mt][nt], 0, 0, 0);
    }
    __syncthreads();
  }
  #pragma unroll
  for (int mt = 0; mt < 4; ++mt)
    #pragma unroll
    for (int nt = 0; nt < 4; ++nt) {
      int col = n0 + wn * 64 + nt * 16 + l15;
      float bv = bias[col];
      #pragma unroll
      for (int r = 0; r < 4; ++r) {
        int row = m0 + wm * 64 + mt * 16 + quad * 4 + r;
        xp[(size_t)row * NG + col] = (unsigned short)f2bf(acc[mt][nt][r] + bv);
      }
    }
}

// ---- shared scan body (round-4 verbatim: 128-VGPR allocation, no spill) ----
// Round-5 lesson: restructuring this loop (carrying zacc/oacc across extra
// barrier regions) made the allocator SPILL the 128-reg whb fragments
// (VGPR_Count 128->92, fused 2211->6476us). Treat this register schedule as
// fragile: do not add loop-carried state.
// FUSED protocol (round-3/4 lessons): producer publishes done tag with a
// RELEASE atomic store; consumer reads xp payload with AGENT-scope relaxed
// atomic u32 loads (stale-local-L2-proof -- same primitive as the mail spin).
template <bool FUSED>
static __device__ __forceinline__ void scan_body(
    char* smem,
    const unsigned short* __restrict__ xp,
    const int* __restrict__ is_new,
    const float* __restrict__ carry_c,
    const float* __restrict__ carry_h,
    const float* __restrict__ Wh,
    const float* __restrict__ Wa,
    const float* __restrict__ ba,
    const float* __restrict__ Wv,
    const float* __restrict__ bv,
    float* __restrict__ out,
    unsigned int* __restrict__ mail,
    unsigned int* __restrict__ done) {
  const int tid  = threadIdx.x;
  const int lane = tid & 63;
  const int w    = tid >> 6;          // wave 0..7
  const int quad = (lane >> 4);
  const int l15  = lane & 15;
  const int bid  = blockIdx.x;        // 0..31
  const int grp  = bid >> 1;
  const int p    = bid & 1;           // half
  const int s    = p * 8 + w;         // j-slice 0..15
  const int b0   = grp * 16;
  const int j0   = s * 16;

  short (*h_lds)[264]  = (short (*)[264])smem;           // bf16 full rows, +8 pad
  int   (*flag_lds)[16] = (int (*)[16])(smem + 8448);    // dbuf by t&1

  // ---- loop-invariant Wh B-fragments -> 128 VGPRs ----
  bf8 whb[4][8];
  #pragma unroll
  for (int nt = 0; nt < 4; ++nt)
    #pragma unroll
    for (int ks = 0; ks < 8; ++ks)
      #pragma unroll
      for (int j = 0; j < 8; ++j) {
        int k = ks * 32 + quad * 8 + j;            // B-frag: k = quad*8+j, n = lane&15
        int col = nt * 256 + j0 + l15;
        whb[nt][ks][j] = f2bf(Wh[(size_t)k * NG + col]);
      }
  // ---- Wa/Wv B-fragments (head GEMM) ----
  const int astart = (s < 15) ? (2 * s) : 30;
  const int ncols  = (s < 15) ? 2 : 3;
  bf8 wab[8];
  #pragma unroll
  for (int ks = 0; ks < 8; ++ks)
    #pragma unroll
    for (int j = 0; j < 8; ++j) {
      int k = ks * 32 + quad * 8 + j;
      float v = 0.0f;
      if (l15 < ncols) {
        int a = astart + l15;
        v = (a < 32) ? Wa[(size_t)k * 32 + a] : Wv[k];
      }
      wab[ks][j] = f2bf(v);
    }
  float obias = 0.0f;
  if (l15 < ncols) {
    int a = astart + l15;
    obias = (a < 32) ? ba[a] : bv[0];
  }
  // ---- carry c in registers ----
  float c4[4];
  #pragma unroll
  for (int r = 0; r < 4; ++r)
    c4[r] = carry_c[(size_t)(b0 + quad * 4 + r) * HH + j0 + l15];

  const int crow = tid >> 5;          // 0..15
  const int cc0  = (tid & 31) * 4;    // 0..124

  bool rdy = false;                   // done[t] already confirmed (lookahead)

  #pragma unroll 1
  for (int t = 0; t <= TT; ++t) {
    const bool last = (t == TT);
    unsigned short xpraw[16];
    unsigned int dv = 0u;             // lookahead sample of done[t+1]
    if (!last) {
      if constexpr (FUSED) {
        // gate xp[t] reads on producer completion
        if (!rdy) {
          const unsigned int want = 0x5EED0000u | (unsigned)t;
          unsigned int* dp = done + (size_t)t * 16 + l15;
          int g2 = 0;
          for (;;) {
            unsigned int v = __hip_atomic_load(dp, __ATOMIC_RELAXED, __HIP_MEMORY_SCOPE_AGENT);
            if (__all((int)(v == want))) break;
            __builtin_amdgcn_s_sleep(8);
            if (++g2 > (1 << 20)) break;   // anti-hang bailout
          }
        }
        __atomic_signal_fence(__ATOMIC_ACQUIRE);
      }
      // prefetch xp + reset flags before the mail spin (independent of h).
      // FUSED: agent-scope u32 atomic loads (lane pairs share a word) --
      // LLC ground truth, immune to stale local L1/L2 lines.
      #pragma unroll
      for (int nt = 0; nt < 4; ++nt)
        #pragma unroll
        for (int r = 0; r < 4; ++r) {
          size_t row = (size_t)t * BB + b0 + quad * 4 + r;
          if constexpr (FUSED) {
            size_t col = (size_t)nt * 256 + j0 + (l15 & ~1);
            unsigned int v = __hip_atomic_load(
                (unsigned int*)(xp + row * NG + col),
                __ATOMIC_RELAXED, __HIP_MEMORY_SCOPE_AGENT);
            xpraw[nt * 4 + r] =
                (unsigned short)((l15 & 1) ? (v >> 16) : (v & 0xFFFFu));
          } else {
            xpraw[nt * 4 + r] = xp[row * NG + nt * 256 + j0 + l15];
          }
        }
      if (tid < 16) flag_lds[t & 1][tid] = is_new[t * BB + b0 + tid];
      if constexpr (FUSED) {
        // issue the lookahead sample now; its latency hides under the mail wait
        if (t + 1 < TT)
          dv = __hip_atomic_load(done + (size_t)(t + 1) * 16 + l15,
                                 __ATOMIC_RELAXED, __HIP_MEMORY_SCOPE_AGENT);
      }
    }
    // ---- acquire partner half: poll own 16B of tagged mail ----
    if (t > 0) {
      unsigned long long* mp = (unsigned long long*)
          (mail + ((((size_t)(t & 1) * 16 + grp) * 2 + (1 - p)) * 2048)
                + (size_t)crow * 128 + cc0);
      const unsigned long long M = 0xFFFF0000FFFF0000ull;
      const unsigned long long Wt = ((unsigned long long)(unsigned)t << 16)
                                  | ((unsigned long long)(unsigned)t << 48);
      unsigned long long pv0, pv1;
      int guard = 0;
      for (;;) {
        pv0 = __hip_atomic_load(&mp[0], __ATOMIC_RELAXED, __HIP_MEMORY_SCOPE_AGENT);
        pv1 = __hip_atomic_load(&mp[1], __ATOMIC_RELAXED, __HIP_MEMORY_SCOPE_AGENT);
        bool ok = ((pv0 & M) == Wt) && ((pv1 & M) == Wt);
        if (__all((int)ok)) break;
        __builtin_amdgcn_s_sleep(1);
        if (++guard > (1 << 24)) break;   // anti-hang bailout
      }
      __atomic_signal_fence(__ATOMIC_ACQUIRE);
      unsigned long long packed =
            (pv0 & 0xFFFFull)
          | (((pv0 >> 32) & 0xFFFFull) << 16)
          | ((pv1 & 0xFFFFull) << 32)
          | (((pv1 >> 32) & 0xFFFFull) << 48);
      *(unsigned long long*)&h_lds[crow][(1 - p) * 128 + cc0] = packed;
    } else {
      // t==0: stage full rows from carry_h (fp32 -> bf16)
      int row  = tid >> 5;
      int col0 = (tid & 31) * 8;
      const float4* src = (const float4*)(carry_h + (size_t)(b0 + row) * HH + col0);
      float4 a = src[0], b4 = src[1];
      bf8 tv;
      tv[0] = f2bf(a.x);  tv[1] = f2bf(a.y);  tv[2] = f2bf(a.z);  tv[3] = f2bf(a.w);
      tv[4] = f2bf(b4.x); tv[5] = f2bf(b4.y); tv[6] = f2bf(b4.z); tv[7] = f2bf(b4.w);
      *(bf8*)&h_lds[row][col0] = tv;
    }
    __syncthreads();   // B2: staging complete
    // ---- A-fragments of h ----
    bf8 af[8];
    #pragma unroll
    for (int ks = 0; ks < 8; ++ks)
      af[ks] = *(const bf8*)&h_lds[l15][ks * 32 + quad * 8];
    __syncthreads();   // B3: reads done -> own half writable below
    if (!last) {
      // ---- z = h @ Wh ----
      f32x4 zacc[4];
      #pragma unroll
      for (int nt = 0; nt < 4; ++nt) zacc[nt] = (f32x4){0.f, 0.f, 0.f, 0.f};
      #pragma unroll
      for (int ks = 0; ks < 8; ++ks)
        #pragma unroll
        for (int nt = 0; nt < 4; ++nt)
          zacc[nt] = __builtin_amdgcn_mfma_f32_16x16x32_bf16(af[ks], whb[nt][ks], zacc[nt], 0, 0, 0);
      // ---- gates; episode reset folded in at the gate level ----
      unsigned int* mout = mail + ((((size_t)((t + 1) & 1) * 16 + grp) * 2 + p) * 2048);
      const unsigned int tag = (unsigned int)(t + 1) << 16;
      #pragma unroll
      for (int r = 0; r < 4; ++r) {
        int fr = flag_lds[t & 1][quad * 4 + r];
        float zi = (fr ? 0.0f : zacc[0][r]) + bf2f(xpraw[0 * 4 + r]);
        float zf = (fr ? 0.0f : zacc[1][r]) + bf2f(xpraw[1 * 4 + r]);
        float zg = (fr ? 0.0f : zacc[2][r]) + bf2f(xpraw[2 * 4 + r]);
        float zo = (fr ? 0.0f : zacc[3][r]) + bf2f(xpraw[3 * 4 + r]);
        float ce = fr ? 0.0f : c4[r];
        float ncv = sigf(zf) * ce + sigf(zi) * tanh_(zg);
        c4[r] = ncv;
        float nh = sigf(zo) * tanh_(ncv);
        unsigned short hv = (unsigned short)f2bf(nh);
        int row = quad * 4 + r;
        h_lds[row][j0 + l15] = (short)hv;                 // own half, block-local
        __hip_atomic_store(&mout[(size_t)row * 128 + w * 16 + l15],
                           (unsigned int)hv | tag,
                           __ATOMIC_RELAXED, __HIP_MEMORY_SCOPE_AGENT);
      }
    }
    if constexpr (FUSED) {
      rdy = (!last && (t + 1 < TT))
          ? (bool)__all((int)(dv == (0x5EED0000u | (unsigned)(t + 1))))
          : false;
    }
    // ---- heads + out for step t-1 AFTER the h handoff: off critical path ----
    if (t > 0) {
      f32x4 oacc = {0.f, 0.f, 0.f, 0.f};
      #pragma unroll
      for (int ks = 0; ks < 8; ++ks)
        oacc = __builtin_amdgcn_mfma_f32_16x16x32_bf16(af[ks], wab[ks], oacc, 0, 0, 0);
      if (l15 < ncols) {
        #pragma unroll
        for (int r = 0; r < 4; ++r) {
          size_t orow = (size_t)(t - 1) * BB + b0 + quad * 4 + r;
          out[orow * 33 + astart + l15] = oacc[r] + obias;
        }
      }
    }
  }
}

// legacy standalone scan (fallback)
__global__ __launch_bounds__(512, 1) void scan_kernel(
    const unsigned short* __restrict__ xp,
    const int* __restrict__ is_new,
    const float* __restrict__ carry_c,
    const float* __restrict__ carry_h,
    const float* __restrict__ Wh,
    const float* __restrict__ Wa,
    const float* __restrict__ ba,
    const float* __restrict__ Wv,
    const float* __restrict__ bv,
    float* __restrict__ out,
    unsigned int* __restrict__ mail) {
  __shared__ __align__(16) char smem[8576];
  scan_body<false>(smem, xp, is_new, carry_c, carry_h, Wh, Wa, ba, Wv, bv,
                   out, mail, nullptr);
}

// ---- fused producer-consumer kernel ----
// blocks 0..31: persistent scan (round-4 body). blocks 32..159: persistent
// GEMM producers, paced by block count only. LDS 84KB forces 1 block/CU
// (round-1 lesson: no issue-slot stealing); 160 blocks <= 256 CUs => all
// resident, no dispatch-order deadlock; all spins have bounded guards.
__global__ __launch_bounds__(512, 1) void fused_kernel(
    const float* __restrict__ X,
    const unsigned short* __restrict__ WxT,
    const float* __restrict__ bias,
    unsigned short* __restrict__ xp,
    const int* __restrict__ is_new,
    const float* __restrict__ carry_c,
    const float* __restrict__ carry_h,
    const float* __restrict__ Wh,
    const float* __restrict__ Wa,
    const float* __restrict__ ba,
    const float* __restrict__ Wv,
    const float* __restrict__ bv,
    float* __restrict__ out,
    unsigned int* __restrict__ mail,
    unsigned int* __restrict__ done) {
  __shared__ __align__(16) char smem[86016];  // 84KB: forces 1 block/CU
  const int tid = threadIdx.x;
  if (blockIdx.x >= 32) {
    // ---------------- persistent GEMM producer ----------------
    short (*As)[72] = (short (*)[72])smem;
    short (*Bs)[72] = (short (*)[72])(smem + 18432);
    short* xps = (short*)smem;        // epilogue staging, overlays As/Bs
    const int lane = tid & 63;
    const int wave = tid >> 6;        // 0..7
    const int quad = lane >> 4;
    const int l15  = lane & 15;
    const int wm = wave >> 1;         // 0..3  (32 rows each)
    const int wn = wave & 1;          // 0..1  (64 cols each)
    const int pid = (int)blockIdx.x - 32;

    for (int tile = pid; tile < 8192; tile += NPROD) {
      const int mtile = tile >> 3;    // 0..1023, ascending per block
      const int nb    = tile & 7;
      const int t16   = mtile >> 1;   // timestep this tile belongs to
      const int m0 = mtile * 128;
      const int n0 = nb * 128;

      f32x4 acc[2][4];
      #pragma unroll
      for (int i = 0; i < 2; ++i)
        #pragma unroll
        for (int j = 0; j < 4; ++j) acc[i][j] = (f32x4){0.f, 0.f, 0.f, 0.f};

      for (int kt = 0; kt < 8; ++kt) {
        const int k0 = kt * 64;
        #pragma unroll
        for (int jj = 0; jj < 2; ++jj) {
          int c = tid + jj * 512;       // 1024 16B-chunks
          int row = c >> 3;
          int kc = (c & 7) * 8;
          const float4* src = (const float4*)(X + (size_t)(m0 + row) * DD + k0 + kc);
          float4 v0 = src[0];
          float4 v1 = src[1];
          bf8 tv;
          tv[0] = f2bf(v0.x); tv[1] = f2bf(v0.y); tv[2] = f2bf(v0.z); tv[3] = f2bf(v0.w);
          tv[4] = f2bf(v1.x); tv[5] = f2bf(v1.y); tv[6] = f2bf(v1.z); tv[7] = f2bf(v1.w);
          *(bf8*)&As[row][kc] = tv;
          const uint4* bsrc = (const uint4*)(WxT + (size_t)(n0 + row) * DD + k0 + kc);
          *(uint4*)&Bs[row][kc] = *bsrc;
        }
        __syncthreads();
        #pragma unroll
        for (int ks = 0; ks < 2; ++ks) {
          bf8 a[2], b[4];
          #pragma unroll
          for (int mt = 0; mt < 2; ++mt)
            a[mt] = *(const bf8*)&As[wm * 32 + mt * 16 + l15][ks * 32 + quad * 8];
          #pragma unroll
          for (int nt = 0; nt < 4; ++nt)
            b[nt] = *(const bf8*)&Bs[wn * 64 + nt * 16 + l15][ks * 32 + quad * 8];
          #pragma unroll
          for (int mt = 0; mt < 2; ++mt)
            #pragma unroll
            for (int nt = 0; nt < 4; ++nt)
              acc[mt][nt] = __builtin_amdgcn_mfma_f32_16x16x32_bf16(a[mt], b[nt], acc[mt][nt], 0, 0, 0);
        }
        __syncthreads();
      }
      // ---- epilogue: stage tile in LDS, then full-line coalesced stores ----
      #pragma unroll
      for (int mt = 0; mt < 2; ++mt)
        #pragma unroll
        for (int nt = 0; nt < 4; ++nt) {
          int lcol = wn * 64 + nt * 16 + l15;
          float bvv = bias[n0 + lcol];
          #pragma unroll
          for (int r = 0; r < 4; ++r) {
            int lrow = wm * 32 + mt * 16 + quad * 4 + r;
            xps[lrow * 136 + lcol] = f2bf(acc[mt][nt][r] + bvv);  // +8 pad rows
          }
        }
      __syncthreads();
      #pragma unroll
      for (int j = 0; j < 4; ++j) {
        int c = tid + j * 512;          // 2048 16B segments
        int row = c >> 4;
        int seg = c & 15;
        uint4 v = *(const uint4*)&xps[row * 136 + seg * 8];
        *(uint4*)(xp + (size_t)(m0 + row) * NG + n0 + seg * 8) = v;
      }
      __syncthreads();  // all waves: vmcnt drained (stores in L2), xps reads done
      if (tid == 0) {
        // RELEASE store: memory model guarantees all prior xp stores are
        // agent-visible before the tag lands.
        const int slot = (mtile & 1) * 8 + nb;
        __hip_atomic_store(&done[(size_t)t16 * 16 + slot],
                           0x5EED0000u | (unsigned)t16,
                           __ATOMIC_RELEASE, __HIP_MEMORY_SCOPE_AGENT);
      }
    }
    return;
  }
  // ---------------- scan consumer ----------------
  scan_body<true>(smem, xp, is_new, carry_c, carry_h, Wh, Wa, ba, Wv, bv,
                  out, mail, done);
}

extern "C" void kernel_launch(void* const* d_in, const int* in_sizes, int n_in,
                              void* d_out, int out_size, void* d_ws, size_t ws_size,
                              hipStream_t stream) {
  const float* X       = (const float*)d_in[0];
  const int* is_new    = (const int*)d_in[1];
  const float* carry_c = (const float*)d_in[2];
  const float* carry_h = (const float*)d_in[3];
  const float* Wx      = (const float*)d_in[4];
  const float* Wh      = (const float*)d_in[5];
  const float* b       = (const float*)d_in[6];
  const float* Wa      = (const float*)d_in[7];
  const float* ba      = (const float*)d_in[8];
  const float* Wv      = (const float*)d_in[9];
  const float* bv      = (const float*)d_in[10];
  float* out = (float*)d_out;
  char* ws = (char*)d_ws;
  if (ws_size < WS_NEEDED) return;  // diagnostic: out stays poisoned
  unsigned short* xp   = (unsigned short*)(ws + XP_OFF);
  unsigned short* WxT  = (unsigned short*)(ws + WXT_OFF);
  unsigned int* mail   = (unsigned int*)(ws + MAIL_OFF);

  hipLaunchKernelGGL(transpose_wx_kernel, dim3(512), dim3(256), 0, stream, Wx, WxT);
  if (ws_size >= WS_NEEDED_FUSE) {
    unsigned int* done = (unsigned int*)(ws + DONE_OFF);
    hipLaunchKernelGGL(fused_kernel, dim3(32 + NPROD), dim3(512), 0, stream,
                       X, WxT, b, xp, is_new, carry_c, carry_h, Wh, Wa, ba, Wv, bv,
                       out, mail, done);
  } else {
    hipLaunchKernelGGL(gemm_xproj, dim3(8192), dim3(256), 0, stream, X, WxT, b, xp);
    hipLaunchKernelGGL(scan_kernel, dim3(32), dim3(512), 0, stream,
                       xp, is_new, carry_c, carry_h, Wh, Wa, ba, Wv, bv, out, mail);
  }
}

// Round 7
// 2438.799 us; speedup vs baseline: 2.7583x; 1.3426x over previous
//
#include <hip/hip_runtime.h>
#include <hip/hip_bf16.h>
#include <stdint.h>

#define TT 512
#define BB 256
#define DD 512
#define HH 256
#define AA 32
#define NG 1024  // 4*H

#define NPROD 128   // persistent producer blocks: 32+128=160 <= 256 CUs.
                    // Pacing by COUNT only (round-4 lesson: no shared throttle).

using f32x4 = __attribute__((ext_vector_type(4))) float;
using bf8   = __attribute__((ext_vector_type(8))) short;

static __device__ __forceinline__ short f2bf(float f) {
  union { float f; uint32_t u; } v; v.f = f;
  uint32_t u = v.u;
  u = u + 0x7fffu + ((u >> 16) & 1u);   // round-to-nearest-even
  return (short)(u >> 16);
}
static __device__ __forceinline__ float bf2f(unsigned short s) {
  union { uint32_t u; float f; } v; v.u = ((uint32_t)s) << 16;
  return v.f;
}
static __device__ __forceinline__ float sigf(float x) {
  return 1.0f / (1.0f + __expf(-x));
}
static __device__ __forceinline__ float tanh_(float x) {
  float e = __expf(2.0f * x);
  return 1.0f - 2.0f / (e + 1.0f);   // safe at +/-inf
}

// ---- workspace layout ----
// Fused path reinterprets the XP region as a consumer-addressed mailbox:
//   xpm u64[T][32 bid][4 gate][512 tid]  (4 bf16 rows packed per u64)
//   = 512*32*4*512*8 = 268435456 B  (exactly XP_BYTES)
// Legacy fallback still uses row-major bf16 xp[T*B][1024] in the same region.
static constexpr size_t XP_OFF    = 0;
static constexpr size_t XP_BYTES  = (size_t)TT * BB * NG * 2;       // 268435456
static constexpr size_t WXT_OFF   = XP_OFF + XP_BYTES;              // bf16 [1024][512]
static constexpr size_t WXT_BYTES = (size_t)NG * DD * 2;            // 1048576
// tagged mail: u32 {low16 = bf16 h, high16 = tag = t+1}
// [parity 2][grp 16][half 2][row 16][hcol 128]
static constexpr size_t MAIL_OFF  = WXT_OFF + WXT_BYTES;
static constexpr size_t MAIL_BYTES= (size_t)2 * 16 * 2 * 16 * 128 * 4;  // 524288
// per-timestep xp readiness tags: u32 done[T][16], value 0x5EED0000|t.
// Poison 0xAAAAAAAA never matches; no init needed (harness poisons ws).
static constexpr size_t DONE_OFF   = MAIL_OFF + MAIL_BYTES;
static constexpr size_t DONE_BYTES = (size_t)TT * 16 * 4;           // 32768
static constexpr size_t WS_NEEDED      = MAIL_OFF + MAIL_BYTES;     // legacy path
static constexpr size_t WS_NEEDED_FUSE = DONE_OFF + DONE_BYTES;     // fused path

// Wx [512][1024] fp32 -> WxT [1024][512] bf16
__global__ __launch_bounds__(256) void transpose_wx_kernel(
    const float* __restrict__ Wx, unsigned short* __restrict__ WxT) {
  __shared__ float tile[32][33];
  int bx = blockIdx.x;
  int k0 = (bx & 15) * 32;
  int n0 = (bx >> 4) * 32;
  int r = threadIdx.x >> 5;
  int c = threadIdx.x & 31;
  #pragma unroll
  for (int i = 0; i < 4; ++i) {
    int rr = r + i * 8;
    tile[rr][c] = Wx[(size_t)(k0 + rr) * NG + n0 + c];
  }
  __syncthreads();
  #pragma unroll
  for (int i = 0; i < 4; ++i) {
    int rr = r + i * 8;
    WxT[(size_t)(n0 + rr) * DD + k0 + c] = (unsigned short)f2bf(tile[c][rr]);
  }
}

// ---- legacy standalone xproj GEMM (fallback when ws lacks done[] space) ----
__global__ __launch_bounds__(256) void gemm_xproj(
    const float* __restrict__ X,
    const unsigned short* __restrict__ WxT,  // [n][k] bf16
    const float* __restrict__ bias,
    unsigned short* __restrict__ xp) {
  __shared__ short As[128][72];
  __shared__ short Bs[128][72];
  const int tid  = threadIdx.x;
  const int lane = tid & 63;
  const int wave = tid >> 6;
  const int quad = lane >> 4;
  const int l15  = lane & 15;
  const int wm = wave >> 1, wn = wave & 1;
  const int bid = blockIdx.x;
  const int m0 = (bid >> 3) * 128;
  const int n0 = (bid & 7) * 128;

  f32x4 acc[4][4];
  #pragma unroll
  for (int i = 0; i < 4; ++i)
    #pragma unroll
    for (int j = 0; j < 4; ++j) acc[i][j] = (f32x4){0.f, 0.f, 0.f, 0.f};

  for (int kt = 0; kt < 8; ++kt) {
    const int k0 = kt * 64;
    #pragma unroll
    for (int jj = 0; jj < 4; ++jj) {
      int c = tid + jj * 256;
      int row = c >> 3;
      int kc = (c & 7) * 8;
      const float4* src = (const float4*)(X + (size_t)(m0 + row) * DD + k0 + kc);
      float4 v0 = src[0];
      float4 v1 = src[1];
      bf8 tv;
      tv[0] = f2bf(v0.x); tv[1] = f2bf(v0.y); tv[2] = f2bf(v0.z); tv[3] = f2bf(v0.w);
      tv[4] = f2bf(v1.x); tv[5] = f2bf(v1.y); tv[6] = f2bf(v1.z); tv[7] = f2bf(v1.w);
      *(bf8*)&As[row][kc] = tv;
      const uint4* bsrc = (const uint4*)(WxT + (size_t)(n0 + row) * DD + k0 + kc);
      *(uint4*)&Bs[row][kc] = *bsrc;
    }
    __syncthreads();
    #pragma unroll
    for (int ks = 0; ks < 2; ++ks) {
      bf8 a[4], b[4];
      #pragma unroll
      for (int mt = 0; mt < 4; ++mt)
        a[mt] = *(const bf8*)&As[wm * 64 + mt * 16 + l15][ks * 32 + quad * 8];
      #pragma unroll
      for (int nt = 0; nt < 4; ++nt)
        b[nt] = *(const bf8*)&Bs[wn * 64 + nt * 16 + l15][ks * 32 + quad * 8];
      #pragma unroll
      for (int mt = 0; mt < 4; ++mt)
        #pragma unroll
        for (int nt = 0; nt < 4; ++nt)
          acc[mt][nt] = __builtin_amdgcn_mfma_f32_16x16x32_bf16(a[mt], b[nt], acc[mt][nt], 0, 0, 0);
    }
    __syncthreads();
  }
  #pragma unroll
  for (int mt = 0; mt < 4; ++mt)
    #pragma unroll
    for (int nt = 0; nt < 4; ++nt) {
      int col = n0 + wn * 64 + nt * 16 + l15;
      float bv = bias[col];
      #pragma unroll
      for (int r = 0; r < 4; ++r) {
        int row = m0 + wm * 64 + mt * 16 + quad * 4 + r;
        xp[(size_t)row * NG + col] = (unsigned short)f2bf(acc[mt][nt][r] + bv);
      }
    }
}

// ---- shared scan body (round-4 register schedule: 128 VGPR, no spill) ----
// Round-5 lesson: do NOT add loop-carried state (whb spills, 3x slowdown).
// FUSED transport (round-6 post-mortem): round-6's 16 scattered agent-atomic
// dword xp loads cost ~800us/dispatch (LLC-direct, uncoalesced, pair-
// duplicated). Now the producer writes a consumer-addressed mailbox
// xpm[t][bid][k][tid] (u64 = 4 bf16 rows), so each thread gates then issues
// just 4 COALESCED agent-atomic u64 loads -- the same proven primitive as
// the mail spin (sound vs stale local L1/L2), at ~1/8 the LLC transactions.
// Gate narrows to the 4 producer tiles this block actually consumes.
template <bool FUSED>
static __device__ __forceinline__ void scan_body(
    char* smem,
    const unsigned short* __restrict__ xp,
    const int* __restrict__ is_new,
    const float* __restrict__ carry_c,
    const float* __restrict__ carry_h,
    const float* __restrict__ Wh,
    const float* __restrict__ Wa,
    const float* __restrict__ ba,
    const float* __restrict__ Wv,
    const float* __restrict__ bv,
    float* __restrict__ out,
    unsigned int* __restrict__ mail,
    unsigned int* __restrict__ done) {
  const int tid  = threadIdx.x;
  const int lane = tid & 63;
  const int w    = tid >> 6;          // wave 0..7
  const int quad = (lane >> 4);
  const int l15  = lane & 15;
  const int bid  = blockIdx.x;        // 0..31
  const int grp  = bid >> 1;
  const int p    = bid & 1;           // half
  const int s    = p * 8 + w;         // j-slice 0..15
  const int b0   = grp * 16;
  const int j0   = s * 16;

  short (*h_lds)[264]  = (short (*)[264])smem;           // bf16 full rows, +8 pad
  int   (*flag_lds)[16] = (int (*)[16])(smem + 8448);    // dbuf by t&1

  // ---- loop-invariant Wh B-fragments -> 128 VGPRs ----
  bf8 whb[4][8];
  #pragma unroll
  for (int nt = 0; nt < 4; ++nt)
    #pragma unroll
    for (int ks = 0; ks < 8; ++ks)
      #pragma unroll
      for (int j = 0; j < 8; ++j) {
        int k = ks * 32 + quad * 8 + j;            // B-frag: k = quad*8+j, n = lane&15
        int col = nt * 256 + j0 + l15;
        whb[nt][ks][j] = f2bf(Wh[(size_t)k * NG + col]);
      }
  // ---- Wa/Wv B-fragments (head GEMM) ----
  const int astart = (s < 15) ? (2 * s) : 30;
  const int ncols  = (s < 15) ? 2 : 3;
  bf8 wab[8];
  #pragma unroll
  for (int ks = 0; ks < 8; ++ks)
    #pragma unroll
    for (int j = 0; j < 8; ++j) {
      int k = ks * 32 + quad * 8 + j;
      float v = 0.0f;
      if (l15 < ncols) {
        int a = astart + l15;
        v = (a < 32) ? Wa[(size_t)k * 32 + a] : Wv[k];
      }
      wab[ks][j] = f2bf(v);
    }
  float obias = 0.0f;
  if (l15 < ncols) {
    int a = astart + l15;
    obias = (a < 32) ? ba[a] : bv[0];
  }
  // ---- carry c in registers ----
  float c4[4];
  #pragma unroll
  for (int r = 0; r < 4; ++r)
    c4[r] = carry_c[(size_t)(b0 + quad * 4 + r) * HH + j0 + l15];

  const int crow = tid >> 5;          // 0..15
  const int cc0  = (tid & 31) * 4;    // 0..124
  // done-gate slot for this block: only the 4 tiles it consumes
  // (mtile = 2t + (grp>>3), nb = 2k+p  ->  slot = (grp>>3)*8 + 2k + p)
  const int dslot = (grp >> 3) * 8 + 2 * (lane & 3) + p;
  const bool dlane = (lane < 4);      // 4 checker lanes per wave

  bool rdy = false;                   // done[t] already confirmed (lookahead)

  #pragma unroll 1
  for (int t = 0; t <= TT; ++t) {
    const bool last = (t == TT);
    unsigned short xpraw[16];
    unsigned int dv = 0u;             // lookahead sample of done[t+1]
    if (!last) {
      if constexpr (FUSED) {
        // gate this step's xpm reads on its 4 producer tiles
        if (!rdy) {
          const unsigned int want = 0x5EED0000u | (unsigned)t;
          unsigned int* dp = done + (size_t)t * 16 + dslot;
          int g2 = 0;
          for (;;) {
            unsigned int v = want;
            if (dlane)
              v = __hip_atomic_load(dp, __ATOMIC_RELAXED, __HIP_MEMORY_SCOPE_AGENT);
            if (__all((int)(v == want))) break;
            __builtin_amdgcn_s_sleep(2);
            if (++g2 > (1 << 20)) break;   // anti-hang bailout
          }
        }
        __atomic_signal_fence(__ATOMIC_ACQUIRE);
      }
      // prefetch xp + reset flags before the mail spin (independent of h)
      if constexpr (FUSED) {
        // 4 coalesced agent-atomic u64 loads from the mailbox
        const unsigned long long* xb = (const unsigned long long*)xp;
        const size_t base = (((size_t)t * 32 + bid) * 4) * 512 + tid;
        unsigned long long xq[4];
        #pragma unroll
        for (int k = 0; k < 4; ++k)
          xq[k] = __hip_atomic_load(xb + base + (size_t)k * 512,
                                    __ATOMIC_RELAXED, __HIP_MEMORY_SCOPE_AGENT);
        #pragma unroll
        for (int k = 0; k < 4; ++k)
          #pragma unroll
          for (int r = 0; r < 4; ++r)
            xpraw[k * 4 + r] = (unsigned short)(xq[k] >> (16 * r));
      } else {
        #pragma unroll
        for (int nt = 0; nt < 4; ++nt)
          #pragma unroll
          for (int r = 0; r < 4; ++r) {
            size_t row = (size_t)t * BB + b0 + quad * 4 + r;
            xpraw[nt * 4 + r] = xp[row * NG + nt * 256 + j0 + l15];
          }
      }
      if (tid < 16) flag_lds[t & 1][tid] = is_new[t * BB + b0 + tid];
      if constexpr (FUSED) {
        // issue the lookahead sample now; its latency hides under the mail wait
        if (t + 1 < TT && dlane)
          dv = __hip_atomic_load(done + (size_t)(t + 1) * 16 + dslot,
                                 __ATOMIC_RELAXED, __HIP_MEMORY_SCOPE_AGENT);
      }
    }
    // ---- acquire partner half: poll own 16B of tagged mail ----
    if (t > 0) {
      unsigned long long* mp = (unsigned long long*)
          (mail + ((((size_t)(t & 1) * 16 + grp) * 2 + (1 - p)) * 2048)
                + (size_t)crow * 128 + cc0);
      const unsigned long long M = 0xFFFF0000FFFF0000ull;
      const unsigned long long Wt = ((unsigned long long)(unsigned)t << 16)
                                  | ((unsigned long long)(unsigned)t << 48);
      unsigned long long pv0, pv1;
      int guard = 0;
      for (;;) {
        pv0 = __hip_atomic_load(&mp[0], __ATOMIC_RELAXED, __HIP_MEMORY_SCOPE_AGENT);
        pv1 = __hip_atomic_load(&mp[1], __ATOMIC_RELAXED, __HIP_MEMORY_SCOPE_AGENT);
        bool ok = ((pv0 & M) == Wt) && ((pv1 & M) == Wt);
        if (__all((int)ok)) break;
        __builtin_amdgcn_s_sleep(1);
        if (++guard > (1 << 24)) break;   // anti-hang bailout
      }
      __atomic_signal_fence(__ATOMIC_ACQUIRE);
      unsigned long long packed =
            (pv0 & 0xFFFFull)
          | (((pv0 >> 32) & 0xFFFFull) << 16)
          | ((pv1 & 0xFFFFull) << 32)
          | (((pv1 >> 32) & 0xFFFFull) << 48);
      *(unsigned long long*)&h_lds[crow][(1 - p) * 128 + cc0] = packed;
    } else {
      // t==0: stage full rows from carry_h (fp32 -> bf16)
      int row  = tid >> 5;
      int col0 = (tid & 31) * 8;
      const float4* src = (const float4*)(carry_h + (size_t)(b0 + row) * HH + col0);
      float4 a = src[0], b4 = src[1];
      bf8 tv;
      tv[0] = f2bf(a.x);  tv[1] = f2bf(a.y);  tv[2] = f2bf(a.z);  tv[3] = f2bf(a.w);
      tv[4] = f2bf(b4.x); tv[5] = f2bf(b4.y); tv[6] = f2bf(b4.z); tv[7] = f2bf(b4.w);
      *(bf8*)&h_lds[row][col0] = tv;
    }
    __syncthreads();   // B2: staging complete
    // ---- A-fragments of h ----
    bf8 af[8];
    #pragma unroll
    for (int ks = 0; ks < 8; ++ks)
      af[ks] = *(const bf8*)&h_lds[l15][ks * 32 + quad * 8];
    __syncthreads();   // B3: reads done -> own half writable below
    if (!last) {
      // ---- z = h @ Wh ----
      f32x4 zacc[4];
      #pragma unroll
      for (int nt = 0; nt < 4; ++nt) zacc[nt] = (f32x4){0.f, 0.f, 0.f, 0.f};
      #pragma unroll
      for (int ks = 0; ks < 8; ++ks)
        #pragma unroll
        for (int nt = 0; nt < 4; ++nt)
          zacc[nt] = __builtin_amdgcn_mfma_f32_16x16x32_bf16(af[ks], whb[nt][ks], zacc[nt], 0, 0, 0);
      // ---- gates; episode reset folded in at the gate level ----
      unsigned int* mout = mail + ((((size_t)((t + 1) & 1) * 16 + grp) * 2 + p) * 2048);
      const unsigned int tag = (unsigned int)(t + 1) << 16;
      #pragma unroll
      for (int r = 0; r < 4; ++r) {
        int fr = flag_lds[t & 1][quad * 4 + r];
        float zi = (fr ? 0.0f : zacc[0][r]) + bf2f(xpraw[0 * 4 + r]);
        float zf = (fr ? 0.0f : zacc[1][r]) + bf2f(xpraw[1 * 4 + r]);
        float zg = (fr ? 0.0f : zacc[2][r]) + bf2f(xpraw[2 * 4 + r]);
        float zo = (fr ? 0.0f : zacc[3][r]) + bf2f(xpraw[3 * 4 + r]);
        float ce = fr ? 0.0f : c4[r];
        float ncv = sigf(zf) * ce + sigf(zi) * tanh_(zg);
        c4[r] = ncv;
        float nh = sigf(zo) * tanh_(ncv);
        unsigned short hv = (unsigned short)f2bf(nh);
        int row = quad * 4 + r;
        h_lds[row][j0 + l15] = (short)hv;                 // own half, block-local
        __hip_atomic_store(&mout[(size_t)row * 128 + w * 16 + l15],
                           (unsigned int)hv | tag,
                           __ATOMIC_RELAXED, __HIP_MEMORY_SCOPE_AGENT);
      }
    }
    if constexpr (FUSED) {
      rdy = (!last && (t + 1 < TT))
          ? (bool)__all((int)(!dlane || (dv == (0x5EED0000u | (unsigned)(t + 1)))))
          : false;
    }
    // ---- heads + out for step t-1 AFTER the h handoff: off critical path ----
    if (t > 0) {
      f32x4 oacc = {0.f, 0.f, 0.f, 0.f};
      #pragma unroll
      for (int ks = 0; ks < 8; ++ks)
        oacc = __builtin_amdgcn_mfma_f32_16x16x32_bf16(af[ks], wab[ks], oacc, 0, 0, 0);
      if (l15 < ncols) {
        #pragma unroll
        for (int r = 0; r < 4; ++r) {
          size_t orow = (size_t)(t - 1) * BB + b0 + quad * 4 + r;
          out[orow * 33 + astart + l15] = oacc[r] + obias;
        }
      }
    }
  }
}

// legacy standalone scan (fallback)
__global__ __launch_bounds__(512, 1) void scan_kernel(
    const unsigned short* __restrict__ xp,
    const int* __restrict__ is_new,
    const float* __restrict__ carry_c,
    const float* __restrict__ carry_h,
    const float* __restrict__ Wh,
    const float* __restrict__ Wa,
    const float* __restrict__ ba,
    const float* __restrict__ Wv,
    const float* __restrict__ bv,
    float* __restrict__ out,
    unsigned int* __restrict__ mail) {
  __shared__ __align__(16) char smem[8576];
  scan_body<false>(smem, xp, is_new, carry_c, carry_h, Wh, Wa, ba, Wv, bv,
                   out, mail, nullptr);
}

// ---- fused producer-consumer kernel ----
// blocks 0..31: persistent scan (round-4 body + mailbox transport).
// blocks 32..159: persistent GEMM producers writing the consumer-addressed
// mailbox directly from acc registers (fully-coalesced 512B/wave u64 runs --
// no LDS epilogue needed), then RELEASE-tagging done[t][slot].
// LDS 84KB forces 1 block/CU (round-1 lesson); 160 blocks <= 256 CUs =>
// all resident, no dispatch-order deadlock; all spins have bounded guards.
__global__ __launch_bounds__(512, 1) void fused_kernel(
    const float* __restrict__ X,
    const unsigned short* __restrict__ WxT,
    const float* __restrict__ bias,
    unsigned short* __restrict__ xp,
    const int* __restrict__ is_new,
    const float* __restrict__ carry_c,
    const float* __restrict__ carry_h,
    const float* __restrict__ Wh,
    const float* __restrict__ Wa,
    const float* __restrict__ ba,
    const float* __restrict__ Wv,
    const float* __restrict__ bv,
    float* __restrict__ out,
    unsigned int* __restrict__ mail,
    unsigned int* __restrict__ done) {
  __shared__ __align__(16) char smem[86016];  // 84KB: forces 1 block/CU
  const int tid = threadIdx.x;
  if (blockIdx.x >= 32) {
    // ---------------- persistent GEMM producer ----------------
    short (*As)[72] = (short (*)[72])smem;
    short (*Bs)[72] = (short (*)[72])(smem + 18432);
    const int lane = tid & 63;
    const int wave = tid >> 6;        // 0..7
    const int quad = lane >> 4;
    const int l15  = lane & 15;
    const int wm = wave >> 1;         // 0..3  (32 rows each)
    const int wn = wave & 1;          // 0..1  (64 cols each)
    const int pid = (int)blockIdx.x - 32;

    for (int tile = pid; tile < 8192; tile += NPROD) {
      const int mtile = tile >> 3;    // 0..1023, ascending per block
      const int nb    = tile & 7;
      const int t16   = mtile >> 1;   // timestep this tile belongs to
      const int m0 = mtile * 128;
      const int n0 = nb * 128;

      f32x4 acc[2][4];
      #pragma unroll
      for (int i = 0; i < 2; ++i)
        #pragma unroll
        for (int j = 0; j < 4; ++j) acc[i][j] = (f32x4){0.f, 0.f, 0.f, 0.f};

      for (int kt = 0; kt < 8; ++kt) {
        const int k0 = kt * 64;
        #pragma unroll
        for (int jj = 0; jj < 2; ++jj) {
          int c = tid + jj * 512;       // 1024 16B-chunks
          int row = c >> 3;
          int kc = (c & 7) * 8;
          const float4* src = (const float4*)(X + (size_t)(m0 + row) * DD + k0 + kc);
          float4 v0 = src[0];
          float4 v1 = src[1];
          bf8 tv;
          tv[0] = f2bf(v0.x); tv[1] = f2bf(v0.y); tv[2] = f2bf(v0.z); tv[3] = f2bf(v0.w);
          tv[4] = f2bf(v1.x); tv[5] = f2bf(v1.y); tv[6] = f2bf(v1.z); tv[7] = f2bf(v1.w);
          *(bf8*)&As[row][kc] = tv;
          const uint4* bsrc = (const uint4*)(WxT + (size_t)(n0 + row) * DD + k0 + kc);
          *(uint4*)&Bs[row][kc] = *bsrc;
        }
        __syncthreads();
        #pragma unroll
        for (int ks = 0; ks < 2; ++ks) {
          bf8 a[2], b[4];
          #pragma unroll
          for (int mt = 0; mt < 2; ++mt)
            a[mt] = *(const bf8*)&As[wm * 32 + mt * 16 + l15][ks * 32 + quad * 8];
          #pragma unroll
          for (int nt = 0; nt < 4; ++nt)
            b[nt] = *(const bf8*)&Bs[wn * 64 + nt * 16 + l15][ks * 32 + quad * 8];
          #pragma unroll
          for (int mt = 0; mt < 2; ++mt)
            #pragma unroll
            for (int nt = 0; nt < 4; ++nt)
              acc[mt][nt] = __builtin_amdgcn_mfma_f32_16x16x32_bf16(a[mt], b[nt], acc[mt][nt], 0, 0, 0);
        }
        __syncthreads();
      }
      // ---- epilogue: pack u64s and store straight into the mailbox ----
      // For each (mt,nt): value (row=wm*32+mt*16+quad*4+r, col=wn*64+nt*16+l15)
      // belongs to consumer block bid_c = ((mtile&1)*8 + wm*2 + mt)*2 + (nb&1),
      // gate slot k = nb>>1, thread tid_c = (wn*4+nt)*64 + lane, packed r=0..3.
      // Per wave per (mt,nt): 64 consecutive u64s -> fully coalesced 512B.
      {
        unsigned long long* xb = (unsigned long long*)xp;
        const int kslot = nb >> 1;
        const int pc    = nb & 1;
        #pragma unroll
        for (int mt = 0; mt < 2; ++mt) {
          const int bid_c = ((mtile & 1) * 8 + wm * 2 + mt) * 2 + pc;
          #pragma unroll
          for (int nt = 0; nt < 4; ++nt) {
            float bvv = bias[n0 + wn * 64 + nt * 16 + l15];
            unsigned long long v = 0;
            #pragma unroll
            for (int r = 0; r < 4; ++r)
              v |= ((unsigned long long)(unsigned short)f2bf(acc[mt][nt][r] + bvv))
                   << (16 * r);
            const int tid_c = (wn * 4 + nt) * 64 + lane;
            xb[(((size_t)t16 * 32 + bid_c) * 4 + kslot) * 512 + tid_c] = v;
          }
        }
      }
      __syncthreads();  // all waves: vmcnt drained -> stores at L2
      if (tid == 0) {
        // RELEASE store: all prior mailbox stores agent-visible before the tag.
        const int slot = (mtile & 1) * 8 + nb;
        __hip_atomic_store(&done[(size_t)t16 * 16 + slot],
                           0x5EED0000u | (unsigned)t16,
                           __ATOMIC_RELEASE, __HIP_MEMORY_SCOPE_AGENT);
      }
    }
    return;
  }
  // ---------------- scan consumer ----------------
  scan_body<true>(smem, xp, is_new, carry_c, carry_h, Wh, Wa, ba, Wv, bv,
                  out, mail, done);
}

extern "C" void kernel_launch(void* const* d_in, const int* in_sizes, int n_in,
                              void* d_out, int out_size, void* d_ws, size_t ws_size,
                              hipStream_t stream) {
  const float* X       = (const float*)d_in[0];
  const int* is_new    = (const int*)d_in[1];
  const float* carry_c = (const float*)d_in[2];
  const float* carry_h = (const float*)d_in[3];
  const float* Wx      = (const float*)d_in[4];
  const float* Wh      = (const float*)d_in[5];
  const float* b       = (const float*)d_in[6];
  const float* Wa      = (const float*)d_in[7];
  const float* ba      = (const float*)d_in[8];
  const float* Wv      = (const float*)d_in[9];
  const float* bv      = (const float*)d_in[10];
  float* out = (float*)d_out;
  char* ws = (char*)d_ws;
  if (ws_size < WS_NEEDED) return;  // diagnostic: out stays poisoned
  unsigned short* xp   = (unsigned short*)(ws + XP_OFF);
  unsigned short* WxT  = (unsigned short*)(ws + WXT_OFF);
  unsigned int* mail   = (unsigned int*)(ws + MAIL_OFF);

  hipLaunchKernelGGL(transpose_wx_kernel, dim3(512), dim3(256), 0, stream, Wx, WxT);
  if (ws_size >= WS_NEEDED_FUSE) {
    unsigned int* done = (unsigned int*)(ws + DONE_OFF);
    hipLaunchKernelGGL(fused_kernel, dim3(32 + NPROD), dim3(512), 0, stream,
                       X, WxT, b, xp, is_new, carry_c, carry_h, Wh, Wa, ba, Wv, bv,
                       out, mail, done);
  } else {
    hipLaunchKernelGGL(gemm_xproj, dim3(8192), dim3(256), 0, stream, X, WxT, b, xp);
    hipLaunchKernelGGL(scan_kernel, dim3(32), dim3(512), 0, stream,
                       xp, is_new, carry_c, carry_h, Wh, Wa, ba, Wv, bv, out, mail);
  }
}